// Round 2
// baseline (6568.437 us; speedup 1.0000x reference)
//
#include <hip/hip_runtime.h>
#include <math.h>

typedef __attribute__((ext_vector_type(8))) _Float16 half8;
typedef __attribute__((ext_vector_type(4))) float floatx4;

#define HMAP 160
#define WMAP 160
#define CIN 1024
#define NCOL 392
#define NCOLP 448
#define NPIX 25600
#define NROI 300
#define NALL 600

// output flat offsets (floats)
#define OUT_CLS      0
#define OUT_CLSRES   1200
#define OUT_CLSSCORE 1800
#define OUT_MASK     2400
#define OUT_ROISALL  237600
#define OUT_BBOX     240600
#define OUT_KEEP     243000

// ---------------------------------------------------------------------------
// Pre-convert W: build Wt_hi/Wt_lo [448][1024] fp16 (transposed, zero-padded
// cols 392..447) + combined bias. lo terms scaled by 4096 to stay fp16-normal.
// ---------------------------------------------------------------------------
__global__ __launch_bounds__(256) void convert_W(
    const float* __restrict__ Wps, const float* __restrict__ bps,
    const float* __restrict__ Wbb, const float* __restrict__ bbb,
    _Float16* __restrict__ Wth, _Float16* __restrict__ Wtl,
    float* __restrict__ bias_c)
{
    const int col = blockIdx.x;      // 0..447
    const int t = threadIdx.x;       // 256 threads, 4 k each
    const bool isps = col < 196;
    const bool valid = col < NCOL;
    const float* W = isps ? Wps : Wbb;
    const int c = isps ? col : col - 196;
    const int k0 = t * 4;
#pragma unroll
    for (int j = 0; j < 4; j++) {
        int k = k0 + j;
        float v = valid ? W[k * 196 + c] : 0.f;
        _Float16 hi = (_Float16)v;
        _Float16 lo = (_Float16)((v - (float)hi) * 4096.f);
        Wth[(size_t)col * CIN + k] = hi;
        Wtl[(size_t)col * CIN + k] = lo;
    }
    if (t == 0)
        bias_c[col] = (col < 196) ? bps[col] : (valid ? bbb[col - 196] : 0.f);
}

// ---------------------------------------------------------------------------
// MFMA GEMM: Ct[col][pix] = feat[pix][k] * Wt[col][k] + bias   (fp16 3-term
// split, fp32-accurate). Block = 128 rows x 64 cols, 4 waves (one 32-row
// strip each, all 64 cols). No LDS / no barriers in K-loop: fragments load
// straight from global (A row-major, W pre-transposed both match the
// A-operand layout A[m=lane&15][k=quad*8+j]). Register double-buffer.
// XCD swizzle: all 7 bn blocks of one bm land on one XCD (L2 A-tile reuse).
// ---------------------------------------------------------------------------
__global__ __launch_bounds__(256) void gemm_mfma(
    const float* __restrict__ A, const _Float16* __restrict__ Bh,
    const _Float16* __restrict__ Bl, const float* __restrict__ bias_c,
    float* __restrict__ Ct)
{
    __shared__ float tr[64 * 129];   // epilogue transpose, +1 pad

    const int id = blockIdx.x;           // 0..1399
    const int xcd = id & 7, g = id >> 3; // round-robin id->XCD heuristic
    const int lin = xcd * 175 + g;       // XCD x owns bm [25x, 25x+25)
    const int bm = lin / 7, bn = lin % 7;

    const int t = threadIdx.x;
    const int lane = t & 63, wave = t >> 6;
    const int l15 = lane & 15, lq = lane >> 4;

    // A: rows bm*128 + wave*32 + s*16 + l15, k = lq*8 + j
    const float* Ap0 = A + (size_t)(bm * 128 + wave * 32 + l15) * CIN + lq * 8;
    const float* Ap1 = Ap0 + (size_t)16 * CIN;
    // B: cols bn*64 + tt*16 + l15, k = lq*8 + j
    const size_t cb = (size_t)(bn * 64 + l15) * CIN + lq * 8;
    const _Float16* Bhp = Bh + cb;
    const _Float16* Blp = Bl + cb;

    floatx4 accM[2][4], accC[2][4];
#pragma unroll
    for (int s = 0; s < 2; s++)
#pragma unroll
        for (int n = 0; n < 4; n++) {
            accM[s][n] = (floatx4){0.f, 0.f, 0.f, 0.f};
            accC[s][n] = (floatx4){0.f, 0.f, 0.f, 0.f};
        }

    floatx4 ra[2][2][2];       // [buf][s][half] : 8 floats per A sub-tile
    half8 rbh[2][4], rbl[2][4];

    // prologue loads (k = 0)
#pragma unroll
    for (int s = 0; s < 2; s++) {
        const float* ap = s ? Ap1 : Ap0;
        ra[0][s][0] = *(const floatx4*)(ap);
        ra[0][s][1] = *(const floatx4*)(ap + 4);
    }
#pragma unroll
    for (int n = 0; n < 4; n++) {
        rbh[0][n] = *(const half8*)(Bhp + (size_t)n * 16 * CIN);
        rbl[0][n] = *(const half8*)(Blp + (size_t)n * 16 * CIN);
    }

    for (int it = 0; it < 32; ++it) {
        const int cur = it & 1, nxt = cur ^ 1;
        if (it < 31) {
            const int kn = (it + 1) * 32;
#pragma unroll
            for (int s = 0; s < 2; s++) {
                const float* ap = (s ? Ap1 : Ap0) + kn;
                ra[nxt][s][0] = *(const floatx4*)(ap);
                ra[nxt][s][1] = *(const floatx4*)(ap + 4);
            }
#pragma unroll
            for (int n = 0; n < 4; n++) {
                rbh[nxt][n] = *(const half8*)(Bhp + (size_t)n * 16 * CIN + kn);
                rbl[nxt][n] = *(const half8*)(Blp + (size_t)n * 16 * CIN + kn);
            }
        }
        // build A fragments (hi + 4096*lo)
        half8 ah[2], al[2];
#pragma unroll
        for (int s = 0; s < 2; s++) {
            half8 h, l;
#pragma unroll
            for (int e = 0; e < 8; e++) {
                float v = (e < 4) ? ra[cur][s][0][e] : ra[cur][s][1][e - 4];
                _Float16 hi = (_Float16)v;
                h[e] = hi;
                l[e] = (_Float16)((v - (float)hi) * 4096.f);
            }
            ah[s] = h; al[s] = l;
        }
#pragma unroll
        for (int s = 0; s < 2; s++)
#pragma unroll
            for (int n = 0; n < 4; n++) {
                accC[s][n] = __builtin_amdgcn_mfma_f32_16x16x32_f16(
                    al[s], rbh[cur][n], accC[s][n], 0, 0, 0);
                accC[s][n] = __builtin_amdgcn_mfma_f32_16x16x32_f16(
                    ah[s], rbl[cur][n], accC[s][n], 0, 0, 0);
                accM[s][n] = __builtin_amdgcn_mfma_f32_16x16x32_f16(
                    ah[s], rbh[cur][n], accM[s][n], 0, 0, 0);
            }
    }

    // epilogue: combine, transpose via LDS, store Ct[col][pix] coalesced
#pragma unroll
    for (int s = 0; s < 2; s++)
#pragma unroll
        for (int n = 0; n < 4; n++) {
            int colL = n * 16 + l15;
            int rowL = wave * 32 + s * 16 + lq * 4;
#pragma unroll
            for (int r = 0; r < 4; r++) {
                float v = accM[s][n][r] + accC[s][n][r] * (1.f / 4096.f);
                tr[colL * 129 + rowL + r] = v;
            }
        }
    __syncthreads();
    {
        const int colL = t >> 2, seg = t & 3;
        const int gcol = bn * 64 + colL;
        if (gcol < NCOL) {
            const float bias = bias_c[gcol];
            float* dst = Ct + (size_t)gcol * NPIX + bm * 128 + seg * 32;
            const float* src = &tr[colL * 129 + seg * 32];
#pragma unroll
            for (int i = 0; i < 8; i++) {
                floatx4 v = *(const floatx4*)(src + i * 4);
                v.x += bias; v.y += bias; v.z += bias; v.w += bias;
                *(floatx4*)(dst + i * 4) = v;
            }
        }
    }
}

// ---------------------------------------------------------------------------
// bilinear setup for transposed maps [plane][160*160]
// ---------------------------------------------------------------------------
__device__ __forceinline__ void bil_setup2(
    float r1, float r2, float r3, float r4, int h, int w,
    int& o00, int& o01, int& o10, int& o11,
    float& w00, float& w01, float& w10, float& w11, int& ij)
{
    float x1 = r1 * 0.125f, y1 = r2 * 0.125f;
    float x2 = r3 * 0.125f, y2 = r4 * 0.125f;
    float bw = (x2 - x1) / 7.0f;
    float bh = (y2 - y1) / 7.0f;
    int i = h >> 1, sy = h & 1, j = w >> 1, sx = w & 1;
    float yy = y1 + ((float)i + ((float)sy + 0.5f) * 0.5f) * bh;
    float xx = x1 + ((float)j + ((float)sx + 0.5f) * 0.5f) * bw;
    float y0f = floorf(yy), x0f = floorf(xx);
    float wy = yy - y0f, wx = xx - x0f;
    int iy0 = min(max((int)y0f, 0), HMAP - 1);
    int iy1 = min(iy0 + 1, HMAP - 1);
    int ix0 = min(max((int)x0f, 0), WMAP - 1);
    int ix1 = min(ix0 + 1, WMAP - 1);
    o00 = iy0 * WMAP + ix0;
    o01 = iy0 * WMAP + ix1;
    o10 = iy1 * WMAP + ix0;
    o11 = iy1 * WMAP + ix1;
    w00 = (1.f - wy) * (1.f - wx);
    w01 = (1.f - wy) * wx;
    w10 = wy * (1.f - wx);
    w11 = wy * wx;
    ij = i * 7 + j;
}

__device__ __forceinline__ float samp(const float* __restrict__ p,
    int o00, int o01, int o10, int o11,
    float w00, float w01, float w10, float w11)
{
    return p[o00] * w00 + p[o01] * w01 + p[o10] * w10 + p[o11] * w11;
}

// ---------------------------------------------------------------------------
// part2_2 over original rois -> offsets -> proposals -> rois_all; bbox[0:300]
// ---------------------------------------------------------------------------
__global__ __launch_bounds__(256) void k_offsets_proposals(
    const float* __restrict__ maps, const float* __restrict__ rois,
    float* __restrict__ ws_roisall, float* __restrict__ out)
{
    const int r = blockIdx.x, t = threadIdx.x;
    __shared__ float4 red[256];
    const float* roi = rois + r * 5;
    const float r0 = roi[0], r1 = roi[1], r2 = roi[2], r3 = roi[3], r4 = roi[4];
    float4 v = make_float4(0.f, 0.f, 0.f, 0.f);
    if (t < 196) {
        int h = t / 14, w = t % 14;
        int o00, o01, o10, o11, ij;
        float w00, w01, w10, w11;
        bil_setup2(r1, r2, r3, r4, h, w, o00, o01, o10, o11, w00, w01, w10, w11, ij);
        float vals[4];
#pragma unroll
        for (int a = 0; a < 4; a++) {
            const float* p = maps + (size_t)(196 + a * 49 + ij) * NPIX;
            vals[a] = samp(p, o00, o01, o10, o11, w00, w01, w10, w11);
        }
        v = make_float4(vals[0], vals[1], vals[2], vals[3]);
    }
    red[t] = v;
    __syncthreads();
    for (int s = 128; s > 0; s >>= 1) {
        if (t < s) {
            red[t].x += red[t + s].x; red[t].y += red[t + s].y;
            red[t].z += red[t + s].z; red[t].w += red[t + s].w;
        }
        __syncthreads();
    }
    if (t == 0) {
        float dx = red[0].x / 196.f, dy = red[0].y / 196.f;
        float dw = red[0].z / 196.f, dh = red[0].w / 196.f;
        out[OUT_BBOX + r * 4 + 0] = dx;
        out[OUT_BBOX + r * 4 + 1] = dy;
        out[OUT_BBOX + r * 4 + 2] = dw;
        out[OUT_BBOX + r * 4 + 3] = dh;
        float w_ = r3 - r1 + 1.f, h_ = r4 - r2 + 1.f;
        float cx = r1 + 0.5f * w_, cy = r2 + 0.5f * h_;
        float pcx = dx * w_ + cx, pcy = dy * h_ + cy;
        float pw = expf(dw) * w_, ph = expf(dh) * h_;
        float px1 = fminf(fmaxf(pcx - 0.5f * pw, 0.f), 1279.f);
        float py1 = fminf(fmaxf(pcy - 0.5f * ph, 0.f), 1279.f);
        float px2 = fminf(fmaxf(pcx + 0.5f * pw, 0.f), 1279.f);
        float py2 = fminf(fmaxf(pcy + 0.5f * ph, 0.f), 1279.f);
        float rowA[5] = {r0, r1, r2, r3, r4};
        float rowB[5] = {0.f, px1, py1, px2, py2};
#pragma unroll
        for (int c = 0; c < 5; c++) {
            ws_roisall[r * 5 + c] = rowA[c];
            ws_roisall[(NROI + r) * 5 + c] = rowB[c];
            out[OUT_ROISALL + r * 5 + c] = rowA[c];
            out[OUT_ROISALL + (NROI + r) * 5 + c] = rowB[c];
        }
    }
}

// ---------------------------------------------------------------------------
// part2_2 over proposals -> bbox[300:600]
// ---------------------------------------------------------------------------
__global__ __launch_bounds__(256) void k_bbox_props(
    const float* __restrict__ maps, const float* __restrict__ ws_roisall,
    float* __restrict__ out)
{
    const int r = blockIdx.x, t = threadIdx.x;
    __shared__ float4 red[256];
    const float* roi = ws_roisall + (NROI + r) * 5;
    const float r1 = roi[1], r2 = roi[2], r3 = roi[3], r4 = roi[4];
    float4 v = make_float4(0.f, 0.f, 0.f, 0.f);
    if (t < 196) {
        int h = t / 14, w = t % 14;
        int o00, o01, o10, o11, ij;
        float w00, w01, w10, w11;
        bil_setup2(r1, r2, r3, r4, h, w, o00, o01, o10, o11, w00, w01, w10, w11, ij);
        float vals[4];
#pragma unroll
        for (int a = 0; a < 4; a++) {
            const float* p = maps + (size_t)(196 + a * 49 + ij) * NPIX;
            vals[a] = samp(p, o00, o01, o10, o11, w00, w01, w10, w11);
        }
        v = make_float4(vals[0], vals[1], vals[2], vals[3]);
    }
    red[t] = v;
    __syncthreads();
    for (int s = 128; s > 0; s >>= 1) {
        if (t < s) {
            red[t].x += red[t + s].x; red[t].y += red[t + s].y;
            red[t].z += red[t + s].z; red[t].w += red[t + s].w;
        }
        __syncthreads();
    }
    if (t == 0) {
        out[OUT_BBOX + (NROI + r) * 4 + 0] = red[0].x / 196.f;
        out[OUT_BBOX + (NROI + r) * 4 + 1] = red[0].y / 196.f;
        out[OUT_BBOX + (NROI + r) * 4 + 2] = red[0].z / 196.f;
        out[OUT_BBOX + (NROI + r) * 4 + 3] = red[0].w / 196.f;
    }
}

// ---------------------------------------------------------------------------
// part2_1 over all 600 rois -> cls, cls_result, cls_score, mask_result
// ---------------------------------------------------------------------------
__global__ __launch_bounds__(256) void k_cls_mask(
    const float* __restrict__ maps, const float* __restrict__ ws_roisall,
    float* __restrict__ scores_ws, float* __restrict__ out)
{
    const int r = blockIdx.x, t = threadIdx.x;
    __shared__ float4 vbuf[196];
    __shared__ float2 red[256];
    __shared__ int s_cr;
    const float* roi = ws_roisall + r * 5;
    const float r1 = roi[1], r2 = roi[2], r3 = roi[3], r4 = roi[4];
    float2 cm = make_float2(0.f, 0.f);
    if (t < 196) {
        int h = t / 14, w = t % 14;
        int o00, o01, o10, o11, ij;
        float w00, w01, w10, w11;
        bil_setup2(r1, r2, r3, r4, h, w, o00, o01, o10, o11, w00, w01, w10, w11, ij);
        float vals[4];
#pragma unroll
        for (int a = 0; a < 4; a++) {
            const float* p = maps + (size_t)(a * 49 + ij) * NPIX;
            vals[a] = samp(p, o00, o01, o10, o11, w00, w01, w10, w11);
        }
        vbuf[t] = make_float4(vals[0], vals[1], vals[2], vals[3]);
        cm.x = fmaxf(vals[0], vals[2]);
        cm.y = fmaxf(vals[1], vals[3]);
    }
    red[t] = cm;
    __syncthreads();
    for (int s = 128; s > 0; s >>= 1) {
        if (t < s) { red[t].x += red[t + s].x; red[t].y += red[t + s].y; }
        __syncthreads();
    }
    if (t == 0) {
        float a0 = red[0].x / 196.f, a1 = red[0].y / 196.f;
        float m = fmaxf(a0, a1);
        float e0 = expf(a0 - m), e1 = expf(a1 - m);
        float inv = 1.f / (e0 + e1);
        float c0 = e0 * inv, c1 = e1 * inv;
        int cr = (a1 > a0) ? 1 : 0;
        float cs = fmaxf(c0, c1);
        out[OUT_CLS + r * 2 + 0] = c0;
        out[OUT_CLS + r * 2 + 1] = c1;
        out[OUT_CLSRES + r] = (float)cr;
        out[OUT_CLSSCORE + r] = cs;
        scores_ws[r] = cs;
        s_cr = cr;
    }
    __syncthreads();
    if (t < 196) {
        int cr = s_cr;
        float4 vv = vbuf[t];
        float v0 = cr ? vv.y : vv.x;
        float v1 = cr ? vv.w : vv.z;
        float m = fmaxf(v0, v1);
        float e0 = expf(v0 - m), e1 = expf(v1 - m);
        float inv = 1.f / (e0 + e1);
        out[OUT_MASK + r * 392 + t * 2 + 0] = e0 * inv;
        out[OUT_MASK + r * 392 + t * 2 + 1] = e1 * inv;
    }
}

// ---------------------------------------------------------------------------
// NMS stage 1: stable descending rank-sort of scores; emit order + sorted boxes
// ---------------------------------------------------------------------------
__global__ __launch_bounds__(640) void k_sort(
    const float* __restrict__ scores_ws, const float* __restrict__ ws_roisall,
    int* __restrict__ order, float* __restrict__ sbox)
{
    __shared__ float ls[NALL];
    __shared__ float lb[NALL][4];
    const int t = threadIdx.x;
    if (t < NALL) {
        ls[t] = scores_ws[t];
        lb[t][0] = ws_roisall[t * 5 + 1];
        lb[t][1] = ws_roisall[t * 5 + 2];
        lb[t][2] = ws_roisall[t * 5 + 3];
        lb[t][3] = ws_roisall[t * 5 + 4];
    }
    __syncthreads();
    if (t < NALL) {
        float s = ls[t];
        int rank = 0;
        for (int j = 0; j < NALL; j++) {
            float sj = ls[j];
            rank += (sj > s) || (sj == s && j < t);
        }
        order[rank] = t;
        float x1 = lb[t][0], y1 = lb[t][1], x2 = lb[t][2], y2 = lb[t][3];
        sbox[rank]            = x1;
        sbox[NALL + rank]     = y1;
        sbox[2 * NALL + rank] = x2;
        sbox[3 * NALL + rank] = y2;
        sbox[4 * NALL + rank] = fmaxf(x2 - x1, 0.f) * fmaxf(y2 - y1, 0.f);
    }
}

// ---------------------------------------------------------------------------
// NMS stage 2: per sorted box i, 600-bit (iou>thr) mask as 10 uint64 words
// ---------------------------------------------------------------------------
__global__ __launch_bounds__(640) void k_iou_mask(
    const float* __restrict__ sbox, unsigned long long* __restrict__ mask)
{
    const int i = blockIdx.x, t = threadIdx.x;
    const float ix1 = sbox[i], iy1 = sbox[NALL + i];
    const float ix2 = sbox[2 * NALL + i], iy2 = sbox[3 * NALL + i];
    const float ia = sbox[4 * NALL + i];
    bool pred = false;
    if (t < NALL) {
        float jx1 = sbox[t], jy1 = sbox[NALL + t];
        float jx2 = sbox[2 * NALL + t], jy2 = sbox[3 * NALL + t];
        float ja = sbox[4 * NALL + t];
        float xx1 = fmaxf(ix1, jx1), yy1 = fmaxf(iy1, jy1);
        float xx2 = fminf(ix2, jx2), yy2 = fminf(iy2, jy2);
        float inter = fmaxf(xx2 - xx1, 0.f) * fmaxf(yy2 - yy1, 0.f);
        float iou = inter / (ia + ja - inter + 1e-8f);
        pred = iou > 0.3f;
    }
    unsigned long long b = __ballot(pred ? 1 : 0);
    if ((t & 63) == 0) mask[(size_t)i * 10 + (t >> 6)] = b;
}

// ---------------------------------------------------------------------------
// NMS stage 3: single-wave greedy suppression + emit keep[300]
// ---------------------------------------------------------------------------
__global__ __launch_bounds__(64) void k_greedy(
    const unsigned long long* __restrict__ mask, const int* __restrict__ order,
    float* __restrict__ out)
{
    const int l = threadIdx.x;
    unsigned long long keepw = 0ull;
    unsigned long long cur = (l < 10) ? mask[l] : 0ull;
    for (int i = 0; i < NALL; i++) {
        unsigned long long nxt =
            (l < 10 && i + 1 < NALL) ? mask[(size_t)(i + 1) * 10 + l] : 0ull;
        bool sup = __any((cur & keepw) != 0ull);
        if (!sup && l == (i >> 6)) keepw |= 1ull << (i & 63);
        cur = nxt;
    }
    __shared__ unsigned long long kw[10];
    if (l < 10) kw[l] = keepw;
    __syncthreads();
    int total = 0;
    for (int w = 0; w < 10; w++) total += __popcll(kw[w]);
    for (int tt = l; tt < 300; tt += 64) {
        float o = -1.f;
        if (tt < total) {
            int rem = tt, s = 0;
            for (int w = 0; w < 10; w++) {
                int pc = __popcll(kw[w]);
                if (rem >= pc) { rem -= pc; continue; }
                unsigned long long word = kw[w];
                while (rem--) word &= word - 1;
                s = w * 64 + (__ffsll((long long)word) - 1);
                break;
            }
            o = (float)order[s];
        }
        out[OUT_KEEP + tt] = o;
    }
}

// ---------------------------------------------------------------------------
extern "C" void kernel_launch(void* const* d_in, const int* in_sizes, int n_in,
                              void* d_out, int out_size, void* d_ws, size_t ws_size,
                              hipStream_t stream)
{
    const float* feat = (const float*)d_in[0];
    const float* Wps  = (const float*)d_in[1];
    const float* bps  = (const float*)d_in[2];
    const float* Wbb  = (const float*)d_in[3];
    const float* bbb  = (const float*)d_in[4];
    const float* rois = (const float*)d_in[5];
    float* out = (float*)d_out;

    // workspace layout
    char* p = (char*)d_ws;
    float* maps_t = (float*)p;                      p += (size_t)NCOL * NPIX * 4;   // 40.14 MB
    _Float16* Wth = (_Float16*)p;                   p += (size_t)NCOLP * CIN * 2;   // 0.92 MB
    _Float16* Wtl = (_Float16*)p;                   p += (size_t)NCOLP * CIN * 2;   // 0.92 MB
    float* bias_c = (float*)p;                      p += NCOLP * 4;
    float* ws_roisall = (float*)p;                  p += NALL * 5 * 4;
    float* scores = (float*)p;                      p += NALL * 4;
    int* order = (int*)p;                           p += NALL * 4;
    float* sbox = (float*)p;                        p += NALL * 5 * 4;
    unsigned long long* mask = (unsigned long long*)p;

    hipLaunchKernelGGL(convert_W, dim3(NCOLP), dim3(256), 0, stream,
                       Wps, bps, Wbb, bbb, Wth, Wtl, bias_c);
    hipLaunchKernelGGL(gemm_mfma, dim3(1400), dim3(256), 0, stream,
                       feat, Wth, Wtl, bias_c, maps_t);
    hipLaunchKernelGGL(k_offsets_proposals, dim3(NROI), dim3(256), 0, stream,
                       maps_t, rois, ws_roisall, out);
    hipLaunchKernelGGL(k_bbox_props, dim3(NROI), dim3(256), 0, stream,
                       maps_t, ws_roisall, out);
    hipLaunchKernelGGL(k_cls_mask, dim3(NALL), dim3(256), 0, stream,
                       maps_t, ws_roisall, scores, out);
    hipLaunchKernelGGL(k_sort, dim3(1), dim3(640), 0, stream,
                       scores, ws_roisall, order, sbox);
    hipLaunchKernelGGL(k_iou_mask, dim3(NALL), dim3(640), 0, stream,
                       sbox, mask);
    hipLaunchKernelGGL(k_greedy, dim3(1), dim3(64), 0, stream,
                       mask, order, out);
}

// Round 3
// 586.044 us; speedup vs baseline: 11.2081x; 11.2081x over previous
//
#include <hip/hip_runtime.h>
#include <math.h>

typedef __attribute__((ext_vector_type(8))) _Float16 half8;
typedef __attribute__((ext_vector_type(4))) float floatx4;

#define HMAP 160
#define WMAP 160
#define CIN 1024
#define NCOL 392
#define NCOLP 448
#define NPIX 25600
#define NROI 300
#define NALL 600

// output flat offsets (floats)
#define OUT_CLS      0
#define OUT_CLSRES   1200
#define OUT_CLSSCORE 1800
#define OUT_MASK     2400
#define OUT_ROISALL  237600
#define OUT_BBOX     240600
#define OUT_KEEP     243000

// ---------------------------------------------------------------------------
// Pre-convert W: build Wt_hi/Wt_lo [448][1024] fp16 (transposed, zero-padded
// cols 392..447) + combined bias. lo terms scaled by 4096 to stay fp16-normal.
// ---------------------------------------------------------------------------
__global__ __launch_bounds__(256) void convert_W(
    const float* __restrict__ Wps, const float* __restrict__ bps,
    const float* __restrict__ Wbb, const float* __restrict__ bbb,
    _Float16* __restrict__ Wth, _Float16* __restrict__ Wtl,
    float* __restrict__ bias_c)
{
    const int col = blockIdx.x;      // 0..447
    const int t = threadIdx.x;       // 256 threads, 4 k each
    const bool isps = col < 196;
    const bool valid = col < NCOL;
    const float* W = isps ? Wps : Wbb;
    const int c = isps ? col : col - 196;
    const int k0 = t * 4;
#pragma unroll
    for (int j = 0; j < 4; j++) {
        int k = k0 + j;
        float v = valid ? W[k * 196 + c] : 0.f;
        _Float16 hi = (_Float16)v;
        _Float16 lo = (_Float16)((v - (float)hi) * 4096.f);
        Wth[(size_t)col * CIN + k] = hi;
        Wtl[(size_t)col * CIN + k] = lo;
    }
    if (t == 0)
        bias_c[col] = (col < 196) ? bps[col] : (valid ? bbb[col - 196] : 0.f);
}

// ---------------------------------------------------------------------------
// MFMA GEMM with STATIC register double-buffering (no runtime-indexed
// register arrays — round-2's 40x VALU explosion came from ra[cur] style
// dynamic indices). Two named buffer structs X/Y; 16 iterations x 2 K-chunks.
// A is read fp32 and split to fp16 hi + 4096*lo in-loop (3-term MFMA,
// fp32-accurate). No LDS / no barriers in K-loop.
// ---------------------------------------------------------------------------
struct Bufs {
    floatx4 a0[2], a1[2];   // raw fp32 A rows (subtile 0: rows+0..15, 1: +16..31)
    half8 bh[4], bl[4];     // B fragments (4 col-tiles of 16)
};

__device__ __forceinline__ void loadb(Bufs& B, int k,
    const float* __restrict__ pA0, const float* __restrict__ pA1,
    const _Float16* __restrict__ pBh, const _Float16* __restrict__ pBl)
{
    B.a0[0] = *(const floatx4*)(pA0 + k);
    B.a0[1] = *(const floatx4*)(pA0 + k + 4);
    B.a1[0] = *(const floatx4*)(pA1 + k);
    B.a1[1] = *(const floatx4*)(pA1 + k + 4);
#pragma unroll
    for (int n = 0; n < 4; n++) {
        B.bh[n] = *(const half8*)(pBh + (size_t)n * 16 * CIN + k);
        B.bl[n] = *(const half8*)(pBl + (size_t)n * 16 * CIN + k);
    }
}

__device__ __forceinline__ void computeb(const Bufs& B,
    floatx4 (&accM)[2][4], floatx4 (&accC)[2][4])
{
    half8 ah[2], al[2];
#pragma unroll
    for (int s = 0; s < 2; s++) {
#pragma unroll
        for (int e = 0; e < 8; e++) {
            float v = (e < 4) ? (s ? B.a1[0][e] : B.a0[0][e])
                              : (s ? B.a1[1][e - 4] : B.a0[1][e - 4]);
            _Float16 hi = (_Float16)v;
            ah[s][e] = hi;
            al[s][e] = (_Float16)((v - (float)hi) * 4096.f);
        }
    }
#pragma unroll
    for (int n = 0; n < 4; n++) {
#pragma unroll
        for (int s = 0; s < 2; s++) {
            accM[s][n] = __builtin_amdgcn_mfma_f32_16x16x32_f16(
                ah[s], B.bh[n], accM[s][n], 0, 0, 0);
            accC[s][n] = __builtin_amdgcn_mfma_f32_16x16x32_f16(
                al[s], B.bh[n], accC[s][n], 0, 0, 0);
            accC[s][n] = __builtin_amdgcn_mfma_f32_16x16x32_f16(
                ah[s], B.bl[n], accC[s][n], 0, 0, 0);
        }
    }
}

__global__ __launch_bounds__(256) void gemm_mfma(
    const float* __restrict__ A, const _Float16* __restrict__ Bh,
    const _Float16* __restrict__ Bl, const float* __restrict__ bias_c,
    float* __restrict__ Ct)
{
    __shared__ float tr[64 * 129];   // epilogue transpose, +1 pad

    const int id = blockIdx.x;           // 0..1399
    const int xcd = id & 7, g = id >> 3; // round-robin id->XCD heuristic
    const int lin = xcd * 175 + g;       // XCD x owns bm [25x, 25x+25)
    const int bm = lin / 7, bn = lin % 7;

    const int t = threadIdx.x;
    const int lane = t & 63, wave = t >> 6;
    const int l15 = lane & 15, lq = lane >> 4;

    // A: rows bm*128 + wave*32 + {0,16} + l15, k = lq*8 + j
    const float* pA0 = A + (size_t)(bm * 128 + wave * 32 + l15) * CIN + lq * 8;
    const float* pA1 = pA0 + (size_t)16 * CIN;
    // B: cols bn*64 + n*16 + l15, k = lq*8 + j
    const size_t cb = (size_t)(bn * 64 + l15) * CIN + lq * 8;
    const _Float16* pBh = Bh + cb;
    const _Float16* pBl = Bl + cb;

    floatx4 accM[2][4], accC[2][4];
#pragma unroll
    for (int s = 0; s < 2; s++)
#pragma unroll
        for (int n = 0; n < 4; n++) {
            accM[s][n] = (floatx4){0.f, 0.f, 0.f, 0.f};
            accC[s][n] = (floatx4){0.f, 0.f, 0.f, 0.f};
        }

    Bufs X, Y;
    loadb(X, 0, pA0, pA1, pBh, pBl);
    loadb(Y, 32, pA0, pA1, pBh, pBl);

#pragma unroll 1
    for (int it = 0; it < 16; ++it) {
        computeb(X, accM, accC);                       // k = it*64
        if (it < 15) loadb(X, it * 64 + 64, pA0, pA1, pBh, pBl);
        computeb(Y, accM, accC);                       // k = it*64 + 32
        if (it < 15) loadb(Y, it * 64 + 96, pA0, pA1, pBh, pBl);
    }

    // epilogue: combine, transpose via LDS, store Ct[col][pix] coalesced
#pragma unroll
    for (int s = 0; s < 2; s++)
#pragma unroll
        for (int n = 0; n < 4; n++) {
            int colL = n * 16 + l15;
            int rowL = wave * 32 + s * 16 + lq * 4;
#pragma unroll
            for (int r = 0; r < 4; r++) {
                float v = accM[s][n][r] + accC[s][n][r] * (1.f / 4096.f);
                tr[colL * 129 + rowL + r] = v;
            }
        }
    __syncthreads();
    {
        const int colL = t >> 2, seg = t & 3;
        const int gcol = bn * 64 + colL;
        if (gcol < NCOL) {
            const float bias = bias_c[gcol];
            float* dst = Ct + (size_t)gcol * NPIX + bm * 128 + seg * 32;
            const float* src = &tr[colL * 129 + seg * 32];
#pragma unroll
            for (int i = 0; i < 8; i++) {
                floatx4 v = *(const floatx4*)(src + i * 4);
                v.x += bias; v.y += bias; v.z += bias; v.w += bias;
                *(floatx4*)(dst + i * 4) = v;
            }
        }
    }
}

// ---------------------------------------------------------------------------
// bilinear setup for transposed maps [plane][160*160]
// ---------------------------------------------------------------------------
__device__ __forceinline__ void bil_setup2(
    float r1, float r2, float r3, float r4, int h, int w,
    int& o00, int& o01, int& o10, int& o11,
    float& w00, float& w01, float& w10, float& w11, int& ij)
{
    float x1 = r1 * 0.125f, y1 = r2 * 0.125f;
    float x2 = r3 * 0.125f, y2 = r4 * 0.125f;
    float bw = (x2 - x1) / 7.0f;
    float bh = (y2 - y1) / 7.0f;
    int i = h >> 1, sy = h & 1, j = w >> 1, sx = w & 1;
    float yy = y1 + ((float)i + ((float)sy + 0.5f) * 0.5f) * bh;
    float xx = x1 + ((float)j + ((float)sx + 0.5f) * 0.5f) * bw;
    float y0f = floorf(yy), x0f = floorf(xx);
    float wy = yy - y0f, wx = xx - x0f;
    int iy0 = min(max((int)y0f, 0), HMAP - 1);
    int iy1 = min(iy0 + 1, HMAP - 1);
    int ix0 = min(max((int)x0f, 0), WMAP - 1);
    int ix1 = min(ix0 + 1, WMAP - 1);
    o00 = iy0 * WMAP + ix0;
    o01 = iy0 * WMAP + ix1;
    o10 = iy1 * WMAP + ix0;
    o11 = iy1 * WMAP + ix1;
    w00 = (1.f - wy) * (1.f - wx);
    w01 = (1.f - wy) * wx;
    w10 = wy * (1.f - wx);
    w11 = wy * wx;
    ij = i * 7 + j;
}

__device__ __forceinline__ float samp(const float* __restrict__ p,
    int o00, int o01, int o10, int o11,
    float w00, float w01, float w10, float w11)
{
    return p[o00] * w00 + p[o01] * w01 + p[o10] * w10 + p[o11] * w11;
}

// ---------------------------------------------------------------------------
// part2_2 over original rois -> offsets -> proposals -> rois_all; bbox[0:300]
// ---------------------------------------------------------------------------
__global__ __launch_bounds__(256) void k_offsets_proposals(
    const float* __restrict__ maps, const float* __restrict__ rois,
    float* __restrict__ ws_roisall, float* __restrict__ out)
{
    const int r = blockIdx.x, t = threadIdx.x;
    __shared__ float4 red[256];
    const float* roi = rois + r * 5;
    const float r0 = roi[0], r1 = roi[1], r2 = roi[2], r3 = roi[3], r4 = roi[4];
    float4 v = make_float4(0.f, 0.f, 0.f, 0.f);
    if (t < 196) {
        int h = t / 14, w = t % 14;
        int o00, o01, o10, o11, ij;
        float w00, w01, w10, w11;
        bil_setup2(r1, r2, r3, r4, h, w, o00, o01, o10, o11, w00, w01, w10, w11, ij);
        float vals[4];
#pragma unroll
        for (int a = 0; a < 4; a++) {
            const float* p = maps + (size_t)(196 + a * 49 + ij) * NPIX;
            vals[a] = samp(p, o00, o01, o10, o11, w00, w01, w10, w11);
        }
        v = make_float4(vals[0], vals[1], vals[2], vals[3]);
    }
    red[t] = v;
    __syncthreads();
    for (int s = 128; s > 0; s >>= 1) {
        if (t < s) {
            red[t].x += red[t + s].x; red[t].y += red[t + s].y;
            red[t].z += red[t + s].z; red[t].w += red[t + s].w;
        }
        __syncthreads();
    }
    if (t == 0) {
        float dx = red[0].x / 196.f, dy = red[0].y / 196.f;
        float dw = red[0].z / 196.f, dh = red[0].w / 196.f;
        out[OUT_BBOX + r * 4 + 0] = dx;
        out[OUT_BBOX + r * 4 + 1] = dy;
        out[OUT_BBOX + r * 4 + 2] = dw;
        out[OUT_BBOX + r * 4 + 3] = dh;
        float w_ = r3 - r1 + 1.f, h_ = r4 - r2 + 1.f;
        float cx = r1 + 0.5f * w_, cy = r2 + 0.5f * h_;
        float pcx = dx * w_ + cx, pcy = dy * h_ + cy;
        float pw = expf(dw) * w_, ph = expf(dh) * h_;
        float px1 = fminf(fmaxf(pcx - 0.5f * pw, 0.f), 1279.f);
        float py1 = fminf(fmaxf(pcy - 0.5f * ph, 0.f), 1279.f);
        float px2 = fminf(fmaxf(pcx + 0.5f * pw, 0.f), 1279.f);
        float py2 = fminf(fmaxf(pcy + 0.5f * ph, 0.f), 1279.f);
        float rowA[5] = {r0, r1, r2, r3, r4};
        float rowB[5] = {0.f, px1, py1, px2, py2};
#pragma unroll
        for (int c = 0; c < 5; c++) {
            ws_roisall[r * 5 + c] = rowA[c];
            ws_roisall[(NROI + r) * 5 + c] = rowB[c];
            out[OUT_ROISALL + r * 5 + c] = rowA[c];
            out[OUT_ROISALL + (NROI + r) * 5 + c] = rowB[c];
        }
    }
}

// ---------------------------------------------------------------------------
// part2_2 over proposals -> bbox[300:600]
// ---------------------------------------------------------------------------
__global__ __launch_bounds__(256) void k_bbox_props(
    const float* __restrict__ maps, const float* __restrict__ ws_roisall,
    float* __restrict__ out)
{
    const int r = blockIdx.x, t = threadIdx.x;
    __shared__ float4 red[256];
    const float* roi = ws_roisall + (NROI + r) * 5;
    const float r1 = roi[1], r2 = roi[2], r3 = roi[3], r4 = roi[4];
    float4 v = make_float4(0.f, 0.f, 0.f, 0.f);
    if (t < 196) {
        int h = t / 14, w = t % 14;
        int o00, o01, o10, o11, ij;
        float w00, w01, w10, w11;
        bil_setup2(r1, r2, r3, r4, h, w, o00, o01, o10, o11, w00, w01, w10, w11, ij);
        float vals[4];
#pragma unroll
        for (int a = 0; a < 4; a++) {
            const float* p = maps + (size_t)(196 + a * 49 + ij) * NPIX;
            vals[a] = samp(p, o00, o01, o10, o11, w00, w01, w10, w11);
        }
        v = make_float4(vals[0], vals[1], vals[2], vals[3]);
    }
    red[t] = v;
    __syncthreads();
    for (int s = 128; s > 0; s >>= 1) {
        if (t < s) {
            red[t].x += red[t + s].x; red[t].y += red[t + s].y;
            red[t].z += red[t + s].z; red[t].w += red[t + s].w;
        }
        __syncthreads();
    }
    if (t == 0) {
        out[OUT_BBOX + (NROI + r) * 4 + 0] = red[0].x / 196.f;
        out[OUT_BBOX + (NROI + r) * 4 + 1] = red[0].y / 196.f;
        out[OUT_BBOX + (NROI + r) * 4 + 2] = red[0].z / 196.f;
        out[OUT_BBOX + (NROI + r) * 4 + 3] = red[0].w / 196.f;
    }
}

// ---------------------------------------------------------------------------
// part2_1 over all 600 rois -> cls, cls_result, cls_score, mask_result
// ---------------------------------------------------------------------------
__global__ __launch_bounds__(256) void k_cls_mask(
    const float* __restrict__ maps, const float* __restrict__ ws_roisall,
    float* __restrict__ scores_ws, float* __restrict__ out)
{
    const int r = blockIdx.x, t = threadIdx.x;
    __shared__ float4 vbuf[196];
    __shared__ float2 red[256];
    __shared__ int s_cr;
    const float* roi = ws_roisall + r * 5;
    const float r1 = roi[1], r2 = roi[2], r3 = roi[3], r4 = roi[4];
    float2 cm = make_float2(0.f, 0.f);
    if (t < 196) {
        int h = t / 14, w = t % 14;
        int o00, o01, o10, o11, ij;
        float w00, w01, w10, w11;
        bil_setup2(r1, r2, r3, r4, h, w, o00, o01, o10, o11, w00, w01, w10, w11, ij);
        float vals[4];
#pragma unroll
        for (int a = 0; a < 4; a++) {
            const float* p = maps + (size_t)(a * 49 + ij) * NPIX;
            vals[a] = samp(p, o00, o01, o10, o11, w00, w01, w10, w11);
        }
        vbuf[t] = make_float4(vals[0], vals[1], vals[2], vals[3]);
        cm.x = fmaxf(vals[0], vals[2]);
        cm.y = fmaxf(vals[1], vals[3]);
    }
    red[t] = cm;
    __syncthreads();
    for (int s = 128; s > 0; s >>= 1) {
        if (t < s) { red[t].x += red[t + s].x; red[t].y += red[t + s].y; }
        __syncthreads();
    }
    if (t == 0) {
        float a0 = red[0].x / 196.f, a1 = red[0].y / 196.f;
        float m = fmaxf(a0, a1);
        float e0 = expf(a0 - m), e1 = expf(a1 - m);
        float inv = 1.f / (e0 + e1);
        float c0 = e0 * inv, c1 = e1 * inv;
        int cr = (a1 > a0) ? 1 : 0;
        float cs = fmaxf(c0, c1);
        out[OUT_CLS + r * 2 + 0] = c0;
        out[OUT_CLS + r * 2 + 1] = c1;
        out[OUT_CLSRES + r] = (float)cr;
        out[OUT_CLSSCORE + r] = cs;
        scores_ws[r] = cs;
        s_cr = cr;
    }
    __syncthreads();
    if (t < 196) {
        int cr = s_cr;
        float4 vv = vbuf[t];
        float v0 = cr ? vv.y : vv.x;
        float v1 = cr ? vv.w : vv.z;
        float m = fmaxf(v0, v1);
        float e0 = expf(v0 - m), e1 = expf(v1 - m);
        float inv = 1.f / (e0 + e1);
        out[OUT_MASK + r * 392 + t * 2 + 0] = e0 * inv;
        out[OUT_MASK + r * 392 + t * 2 + 1] = e1 * inv;
    }
}

// ---------------------------------------------------------------------------
// NMS stage 1: stable descending rank-sort of scores; emit order + sorted boxes
// ---------------------------------------------------------------------------
__global__ __launch_bounds__(640) void k_sort(
    const float* __restrict__ scores_ws, const float* __restrict__ ws_roisall,
    int* __restrict__ order, float* __restrict__ sbox)
{
    __shared__ float ls[NALL];
    __shared__ float lb[NALL][4];
    const int t = threadIdx.x;
    if (t < NALL) {
        ls[t] = scores_ws[t];
        lb[t][0] = ws_roisall[t * 5 + 1];
        lb[t][1] = ws_roisall[t * 5 + 2];
        lb[t][2] = ws_roisall[t * 5 + 3];
        lb[t][3] = ws_roisall[t * 5 + 4];
    }
    __syncthreads();
    if (t < NALL) {
        float s = ls[t];
        int rank = 0;
        for (int j = 0; j < NALL; j++) {
            float sj = ls[j];
            rank += (sj > s) || (sj == s && j < t);
        }
        order[rank] = t;
        float x1 = lb[t][0], y1 = lb[t][1], x2 = lb[t][2], y2 = lb[t][3];
        sbox[rank]            = x1;
        sbox[NALL + rank]     = y1;
        sbox[2 * NALL + rank] = x2;
        sbox[3 * NALL + rank] = y2;
        sbox[4 * NALL + rank] = fmaxf(x2 - x1, 0.f) * fmaxf(y2 - y1, 0.f);
    }
}

// ---------------------------------------------------------------------------
// NMS stage 2: per sorted box i, 600-bit (iou>thr) mask as 10 uint64 words
// ---------------------------------------------------------------------------
__global__ __launch_bounds__(640) void k_iou_mask(
    const float* __restrict__ sbox, unsigned long long* __restrict__ mask)
{
    const int i = blockIdx.x, t = threadIdx.x;
    const float ix1 = sbox[i], iy1 = sbox[NALL + i];
    const float ix2 = sbox[2 * NALL + i], iy2 = sbox[3 * NALL + i];
    const float ia = sbox[4 * NALL + i];
    bool pred = false;
    if (t < NALL) {
        float jx1 = sbox[t], jy1 = sbox[NALL + t];
        float jx2 = sbox[2 * NALL + t], jy2 = sbox[3 * NALL + t];
        float ja = sbox[4 * NALL + t];
        float xx1 = fmaxf(ix1, jx1), yy1 = fmaxf(iy1, jy1);
        float xx2 = fminf(ix2, jx2), yy2 = fminf(iy2, jy2);
        float inter = fmaxf(xx2 - xx1, 0.f) * fmaxf(yy2 - yy1, 0.f);
        float iou = inter / (ia + ja - inter + 1e-8f);
        pred = iou > 0.3f;
    }
    unsigned long long b = __ballot(pred ? 1 : 0);
    if ((t & 63) == 0) mask[(size_t)i * 10 + (t >> 6)] = b;
}

// ---------------------------------------------------------------------------
// NMS stage 3: single-wave greedy suppression + emit keep[300]
// ---------------------------------------------------------------------------
__global__ __launch_bounds__(64) void k_greedy(
    const unsigned long long* __restrict__ mask, const int* __restrict__ order,
    float* __restrict__ out)
{
    const int l = threadIdx.x;
    unsigned long long keepw = 0ull;
    unsigned long long cur = (l < 10) ? mask[l] : 0ull;
    for (int i = 0; i < NALL; i++) {
        unsigned long long nxt =
            (l < 10 && i + 1 < NALL) ? mask[(size_t)(i + 1) * 10 + l] : 0ull;
        bool sup = __any((cur & keepw) != 0ull);
        if (!sup && l == (i >> 6)) keepw |= 1ull << (i & 63);
        cur = nxt;
    }
    __shared__ unsigned long long kw[10];
    if (l < 10) kw[l] = keepw;
    __syncthreads();
    int total = 0;
    for (int w = 0; w < 10; w++) total += __popcll(kw[w]);
    for (int tt = l; tt < 300; tt += 64) {
        float o = -1.f;
        if (tt < total) {
            int rem = tt, s = 0;
            for (int w = 0; w < 10; w++) {
                int pc = __popcll(kw[w]);
                if (rem >= pc) { rem -= pc; continue; }
                unsigned long long word = kw[w];
                while (rem--) word &= word - 1;
                s = w * 64 + (__ffsll((long long)word) - 1);
                break;
            }
            o = (float)order[s];
        }
        out[OUT_KEEP + tt] = o;
    }
}

// ---------------------------------------------------------------------------
extern "C" void kernel_launch(void* const* d_in, const int* in_sizes, int n_in,
                              void* d_out, int out_size, void* d_ws, size_t ws_size,
                              hipStream_t stream)
{
    const float* feat = (const float*)d_in[0];
    const float* Wps  = (const float*)d_in[1];
    const float* bps  = (const float*)d_in[2];
    const float* Wbb  = (const float*)d_in[3];
    const float* bbb  = (const float*)d_in[4];
    const float* rois = (const float*)d_in[5];
    float* out = (float*)d_out;

    // workspace layout
    char* p = (char*)d_ws;
    float* maps_t = (float*)p;                      p += (size_t)NCOL * NPIX * 4;   // 40.14 MB
    _Float16* Wth = (_Float16*)p;                   p += (size_t)NCOLP * CIN * 2;   // 0.92 MB
    _Float16* Wtl = (_Float16*)p;                   p += (size_t)NCOLP * CIN * 2;   // 0.92 MB
    float* bias_c = (float*)p;                      p += NCOLP * 4;
    float* ws_roisall = (float*)p;                  p += NALL * 5 * 4;
    float* scores = (float*)p;                      p += NALL * 4;
    int* order = (int*)p;                           p += NALL * 4;
    float* sbox = (float*)p;                        p += NALL * 5 * 4;
    unsigned long long* mask = (unsigned long long*)p;

    hipLaunchKernelGGL(convert_W, dim3(NCOLP), dim3(256), 0, stream,
                       Wps, bps, Wbb, bbb, Wth, Wtl, bias_c);
    hipLaunchKernelGGL(gemm_mfma, dim3(1400), dim3(256), 0, stream,
                       feat, Wth, Wtl, bias_c, maps_t);
    hipLaunchKernelGGL(k_offsets_proposals, dim3(NROI), dim3(256), 0, stream,
                       maps_t, rois, ws_roisall, out);
    hipLaunchKernelGGL(k_bbox_props, dim3(NROI), dim3(256), 0, stream,
                       maps_t, ws_roisall, out);
    hipLaunchKernelGGL(k_cls_mask, dim3(NALL), dim3(256), 0, stream,
                       maps_t, ws_roisall, scores, out);
    hipLaunchKernelGGL(k_sort, dim3(1), dim3(640), 0, stream,
                       scores, ws_roisall, order, sbox);
    hipLaunchKernelGGL(k_iou_mask, dim3(NALL), dim3(640), 0, stream,
                       sbox, mask);
    hipLaunchKernelGGL(k_greedy, dim3(1), dim3(64), 0, stream,
                       mask, order, out);
}

// Round 4
// 502.775 us; speedup vs baseline: 13.0644x; 1.1656x over previous
//
#include <hip/hip_runtime.h>
#include <math.h>

typedef __attribute__((ext_vector_type(8))) _Float16 half8;
typedef __attribute__((ext_vector_type(4))) float floatx4;

#define HMAP 160
#define WMAP 160
#define CIN 1024
#define NCOL 392
#define NCOLP 448
#define NPIX 25600
#define NROI 300
#define NALL 600

// output flat offsets (floats)
#define OUT_CLS      0
#define OUT_CLSRES   1200
#define OUT_CLSSCORE 1800
#define OUT_MASK     2400
#define OUT_ROISALL  237600
#define OUT_BBOX     240600
#define OUT_KEEP     243000

// ---------------------------------------------------------------------------
// Pre-convert W: build Wt_hi/Wt_lo [448][1024] fp16 (transposed, zero-padded
// cols 392..447) + combined bias. lo terms scaled by 4096 to stay fp16-normal.
// ---------------------------------------------------------------------------
__global__ __launch_bounds__(256) void convert_W(
    const float* __restrict__ Wps, const float* __restrict__ bps,
    const float* __restrict__ Wbb, const float* __restrict__ bbb,
    _Float16* __restrict__ Wth, _Float16* __restrict__ Wtl,
    float* __restrict__ bias_c)
{
    const int col = blockIdx.x;      // 0..447
    const int t = threadIdx.x;       // 256 threads, 4 k each
    const bool isps = col < 196;
    const bool valid = col < NCOL;
    const float* W = isps ? Wps : Wbb;
    const int c = isps ? col : col - 196;
    const int k0 = t * 4;
#pragma unroll
    for (int j = 0; j < 4; j++) {
        int k = k0 + j;
        float v = valid ? W[k * 196 + c] : 0.f;
        _Float16 hi = (_Float16)v;
        _Float16 lo = (_Float16)((v - (float)hi) * 4096.f);
        Wth[(size_t)col * CIN + k] = hi;
        Wtl[(size_t)col * CIN + k] = lo;
    }
    if (t == 0)
        bias_c[col] = (col < 196) ? bps[col] : (valid ? bbb[col - 196] : 0.f);
}

// ---------------------------------------------------------------------------
// MFMA GEMM, latency-tolerant: A prefetched 4 chunks deep (HBM ~900cyc cold
// misses — A is streamed once), B 2 deep (L2-resident). ALL buffer indices
// are compile-time (named structs A0..A3/B0,B1) — dynamic register indexing
// caused round-2's 40x VALU explosion. fp16 3-term split (fp32-accurate),
// lo terms pre-scaled x4096 to stay fp16-normal.
// ---------------------------------------------------------------------------
struct ABuf { floatx4 a[4]; };           // [sub*2+half]: rows {0,16}+l15, 8 k each
struct BBuf { half8 bh[4], bl[4]; };     // 4 col-tiles of 16

__device__ __forceinline__ void loadA(ABuf& A, int k,
    const float* __restrict__ pA0, const float* __restrict__ pA1)
{
    A.a[0] = *(const floatx4*)(pA0 + k);
    A.a[1] = *(const floatx4*)(pA0 + k + 4);
    A.a[2] = *(const floatx4*)(pA1 + k);
    A.a[3] = *(const floatx4*)(pA1 + k + 4);
}

__device__ __forceinline__ void loadB(BBuf& B, int k,
    const _Float16* __restrict__ pBh, const _Float16* __restrict__ pBl)
{
#pragma unroll
    for (int n = 0; n < 4; n++) {
        B.bh[n] = *(const half8*)(pBh + (size_t)n * 16 * CIN + k);
        B.bl[n] = *(const half8*)(pBl + (size_t)n * 16 * CIN + k);
    }
}

__device__ __forceinline__ void computeb(const ABuf& A, const BBuf& B,
    floatx4 (&accM)[2][4], floatx4 (&accC)[2][4])
{
    half8 ah[2], al[2];
#pragma unroll
    for (int s = 0; s < 2; s++) {
#pragma unroll
        for (int e = 0; e < 8; e++) {
            float v = A.a[s * 2 + (e >> 2)][e & 3];
            _Float16 hi = (_Float16)v;
            ah[s][e] = hi;
            al[s][e] = (_Float16)((v - (float)hi) * 4096.f);
        }
    }
#pragma unroll
    for (int n = 0; n < 4; n++) {
#pragma unroll
        for (int s = 0; s < 2; s++) {
            accM[s][n] = __builtin_amdgcn_mfma_f32_16x16x32_f16(
                ah[s], B.bh[n], accM[s][n], 0, 0, 0);
            accC[s][n] = __builtin_amdgcn_mfma_f32_16x16x32_f16(
                al[s], B.bh[n], accC[s][n], 0, 0, 0);
            accC[s][n] = __builtin_amdgcn_mfma_f32_16x16x32_f16(
                ah[s], B.bl[n], accC[s][n], 0, 0, 0);
        }
    }
}

__global__ __launch_bounds__(256) void gemm_mfma(
    const float* __restrict__ A, const _Float16* __restrict__ Bh,
    const _Float16* __restrict__ Bl, const float* __restrict__ bias_c,
    float* __restrict__ Ct)
{
    __shared__ float tr[64 * 129];   // epilogue transpose, +1 pad

    const int id = blockIdx.x;           // 0..1399
    const int xcd = id & 7, g = id >> 3; // round-robin id->XCD heuristic
    const int lin = xcd * 175 + g;       // XCD x owns bm [25x, 25x+25)
    const int bm = lin / 7, bn = lin % 7;

    const int t = threadIdx.x;
    const int lane = t & 63, wave = t >> 6;
    const int l15 = lane & 15, lq = lane >> 4;

    // A: rows bm*128 + wave*32 + {0,16} + l15, k = lq*8 + j
    const float* pA0 = A + (size_t)(bm * 128 + wave * 32 + l15) * CIN + lq * 8;
    const float* pA1 = pA0 + (size_t)16 * CIN;
    // B: cols bn*64 + n*16 + l15, k = lq*8 + j
    const size_t cb = (size_t)(bn * 64 + l15) * CIN + lq * 8;
    const _Float16* pBh = Bh + cb;
    const _Float16* pBl = Bl + cb;

    floatx4 accM[2][4], accC[2][4];
#pragma unroll
    for (int s = 0; s < 2; s++)
#pragma unroll
        for (int n = 0; n < 4; n++) {
            accM[s][n] = (floatx4){0.f, 0.f, 0.f, 0.f};
            accC[s][n] = (floatx4){0.f, 0.f, 0.f, 0.f};
        }

    ABuf A0, A1, A2, A3;
    BBuf B0, B1;
    loadA(A0, 0, pA0, pA1);
    loadA(A1, 32, pA0, pA1);
    loadA(A2, 64, pA0, pA1);
    loadA(A3, 96, pA0, pA1);
    loadB(B0, 0, pBh, pBl);
    loadB(B1, 32, pBh, pBl);

    // chunk c uses A[c%4], B[c%2]; A prefetch distance 4 chunks, B distance 2
#pragma unroll 1
    for (int it = 0; it < 8; ++it) {
        const int kb = it * 128;
        computeb(A0, B0, accM, accC);                 // chunk kb
        if (it < 7) loadA(A0, kb + 128, pA0, pA1);
        loadB(B0, kb + 64, pBh, pBl);                 // <=960 always
        computeb(A1, B1, accM, accC);                 // chunk kb+32
        if (it < 7) loadA(A1, kb + 160, pA0, pA1);
        loadB(B1, kb + 96, pBh, pBl);                 // <=992 always
        computeb(A2, B0, accM, accC);                 // chunk kb+64
        if (it < 7) { loadA(A2, kb + 192, pA0, pA1); loadB(B0, kb + 128, pBh, pBl); }
        computeb(A3, B1, accM, accC);                 // chunk kb+96
        if (it < 7) { loadA(A3, kb + 224, pA0, pA1); loadB(B1, kb + 160, pBh, pBl); }
    }

    // epilogue: combine, transpose via LDS, store Ct[col][pix] coalesced
#pragma unroll
    for (int s = 0; s < 2; s++)
#pragma unroll
        for (int n = 0; n < 4; n++) {
            int colL = n * 16 + l15;
            int rowL = wave * 32 + s * 16 + lq * 4;
#pragma unroll
            for (int r = 0; r < 4; r++) {
                float v = accM[s][n][r] + accC[s][n][r] * (1.f / 4096.f);
                tr[colL * 129 + rowL + r] = v;
            }
        }
    __syncthreads();
    {
        const int colL = t >> 2, seg = t & 3;
        const int gcol = bn * 64 + colL;
        if (gcol < NCOL) {
            const float bias = bias_c[gcol];
            float* dst = Ct + (size_t)gcol * NPIX + bm * 128 + seg * 32;
            const float* src = &tr[colL * 129 + seg * 32];
#pragma unroll
            for (int i = 0; i < 8; i++) {
                floatx4 v = *(const floatx4*)(src + i * 4);
                v.x += bias; v.y += bias; v.z += bias; v.w += bias;
                *(floatx4*)(dst + i * 4) = v;
            }
        }
    }
}

// ---------------------------------------------------------------------------
// bilinear setup for transposed maps [plane][160*160]
// ---------------------------------------------------------------------------
__device__ __forceinline__ void bil_setup2(
    float r1, float r2, float r3, float r4, int h, int w,
    int& o00, int& o01, int& o10, int& o11,
    float& w00, float& w01, float& w10, float& w11, int& ij)
{
    float x1 = r1 * 0.125f, y1 = r2 * 0.125f;
    float x2 = r3 * 0.125f, y2 = r4 * 0.125f;
    float bw = (x2 - x1) / 7.0f;
    float bh = (y2 - y1) / 7.0f;
    int i = h >> 1, sy = h & 1, j = w >> 1, sx = w & 1;
    float yy = y1 + ((float)i + ((float)sy + 0.5f) * 0.5f) * bh;
    float xx = x1 + ((float)j + ((float)sx + 0.5f) * 0.5f) * bw;
    float y0f = floorf(yy), x0f = floorf(xx);
    float wy = yy - y0f, wx = xx - x0f;
    int iy0 = min(max((int)y0f, 0), HMAP - 1);
    int iy1 = min(iy0 + 1, HMAP - 1);
    int ix0 = min(max((int)x0f, 0), WMAP - 1);
    int ix1 = min(ix0 + 1, WMAP - 1);
    o00 = iy0 * WMAP + ix0;
    o01 = iy0 * WMAP + ix1;
    o10 = iy1 * WMAP + ix0;
    o11 = iy1 * WMAP + ix1;
    w00 = (1.f - wy) * (1.f - wx);
    w01 = (1.f - wy) * wx;
    w10 = wy * (1.f - wx);
    w11 = wy * wx;
    ij = i * 7 + j;
}

__device__ __forceinline__ float samp(const float* __restrict__ p,
    int o00, int o01, int o10, int o11,
    float w00, float w01, float w10, float w11)
{
    return p[o00] * w00 + p[o01] * w01 + p[o10] * w10 + p[o11] * w11;
}

// ---------------------------------------------------------------------------
// part2_2 over original rois -> offsets -> proposals -> rois_all; bbox[0:300]
// ---------------------------------------------------------------------------
__global__ __launch_bounds__(256) void k_offsets_proposals(
    const float* __restrict__ maps, const float* __restrict__ rois,
    float* __restrict__ ws_roisall, float* __restrict__ out)
{
    const int r = blockIdx.x, t = threadIdx.x;
    __shared__ float4 red[256];
    const float* roi = rois + r * 5;
    const float r0 = roi[0], r1 = roi[1], r2 = roi[2], r3 = roi[3], r4 = roi[4];
    float4 v = make_float4(0.f, 0.f, 0.f, 0.f);
    if (t < 196) {
        int h = t / 14, w = t % 14;
        int o00, o01, o10, o11, ij;
        float w00, w01, w10, w11;
        bil_setup2(r1, r2, r3, r4, h, w, o00, o01, o10, o11, w00, w01, w10, w11, ij);
        float vals[4];
#pragma unroll
        for (int a = 0; a < 4; a++) {
            const float* p = maps + (size_t)(196 + a * 49 + ij) * NPIX;
            vals[a] = samp(p, o00, o01, o10, o11, w00, w01, w10, w11);
        }
        v = make_float4(vals[0], vals[1], vals[2], vals[3]);
    }
    red[t] = v;
    __syncthreads();
    for (int s = 128; s > 0; s >>= 1) {
        if (t < s) {
            red[t].x += red[t + s].x; red[t].y += red[t + s].y;
            red[t].z += red[t + s].z; red[t].w += red[t + s].w;
        }
        __syncthreads();
    }
    if (t == 0) {
        float dx = red[0].x / 196.f, dy = red[0].y / 196.f;
        float dw = red[0].z / 196.f, dh = red[0].w / 196.f;
        out[OUT_BBOX + r * 4 + 0] = dx;
        out[OUT_BBOX + r * 4 + 1] = dy;
        out[OUT_BBOX + r * 4 + 2] = dw;
        out[OUT_BBOX + r * 4 + 3] = dh;
        float w_ = r3 - r1 + 1.f, h_ = r4 - r2 + 1.f;
        float cx = r1 + 0.5f * w_, cy = r2 + 0.5f * h_;
        float pcx = dx * w_ + cx, pcy = dy * h_ + cy;
        float pw = expf(dw) * w_, ph = expf(dh) * h_;
        float px1 = fminf(fmaxf(pcx - 0.5f * pw, 0.f), 1279.f);
        float py1 = fminf(fmaxf(pcy - 0.5f * ph, 0.f), 1279.f);
        float px2 = fminf(fmaxf(pcx + 0.5f * pw, 0.f), 1279.f);
        float py2 = fminf(fmaxf(pcy + 0.5f * ph, 0.f), 1279.f);
        float rowA[5] = {r0, r1, r2, r3, r4};
        float rowB[5] = {0.f, px1, py1, px2, py2};
#pragma unroll
        for (int c = 0; c < 5; c++) {
            ws_roisall[r * 5 + c] = rowA[c];
            ws_roisall[(NROI + r) * 5 + c] = rowB[c];
            out[OUT_ROISALL + r * 5 + c] = rowA[c];
            out[OUT_ROISALL + (NROI + r) * 5 + c] = rowB[c];
        }
    }
}

// ---------------------------------------------------------------------------
// part2_1 over all 600 rois -> cls, cls_result, cls_score, mask_result
// PLUS (for r >= 300) part2_2 bbox for the proposal rois (reuses the bilinear
// setup) -> bbox[300:600]. One launch fewer than round 3.
// ---------------------------------------------------------------------------
__global__ __launch_bounds__(256) void k_cls_mask(
    const float* __restrict__ maps, const float* __restrict__ ws_roisall,
    float* __restrict__ scores_ws, float* __restrict__ out)
{
    const int r = blockIdx.x, t = threadIdx.x;
    __shared__ float4 vbuf[196];
    __shared__ float2 red[256];
    __shared__ float4 red4[256];
    __shared__ int s_cr;
    const float* roi = ws_roisall + r * 5;
    const float r1 = roi[1], r2 = roi[2], r3 = roi[3], r4 = roi[4];

    int o00 = 0, o01 = 0, o10 = 0, o11 = 0, ij = 0;
    float w00 = 0.f, w01 = 0.f, w10 = 0.f, w11 = 0.f;
    float2 cm = make_float2(0.f, 0.f);
    if (t < 196) {
        int h = t / 14, w = t % 14;
        bil_setup2(r1, r2, r3, r4, h, w, o00, o01, o10, o11, w00, w01, w10, w11, ij);
        float vals[4];
#pragma unroll
        for (int a = 0; a < 4; a++) {
            const float* p = maps + (size_t)(a * 49 + ij) * NPIX;
            vals[a] = samp(p, o00, o01, o10, o11, w00, w01, w10, w11);
        }
        vbuf[t] = make_float4(vals[0], vals[1], vals[2], vals[3]);
        cm.x = fmaxf(vals[0], vals[2]);
        cm.y = fmaxf(vals[1], vals[3]);
    }
    red[t] = cm;
    __syncthreads();
    for (int s = 128; s > 0; s >>= 1) {
        if (t < s) { red[t].x += red[t + s].x; red[t].y += red[t + s].y; }
        __syncthreads();
    }
    if (t == 0) {
        float a0 = red[0].x / 196.f, a1 = red[0].y / 196.f;
        float m = fmaxf(a0, a1);
        float e0 = expf(a0 - m), e1 = expf(a1 - m);
        float inv = 1.f / (e0 + e1);
        float c0 = e0 * inv, c1 = e1 * inv;
        int cr = (a1 > a0) ? 1 : 0;
        float cs = fmaxf(c0, c1);
        out[OUT_CLS + r * 2 + 0] = c0;
        out[OUT_CLS + r * 2 + 1] = c1;
        out[OUT_CLSRES + r] = (float)cr;
        out[OUT_CLSSCORE + r] = cs;
        scores_ws[r] = cs;
        s_cr = cr;
    }
    __syncthreads();
    if (t < 196) {
        int cr = s_cr;
        float4 vv = vbuf[t];
        float v0 = cr ? vv.y : vv.x;
        float v1 = cr ? vv.w : vv.z;
        float m = fmaxf(v0, v1);
        float e0 = expf(v0 - m), e1 = expf(v1 - m);
        float inv = 1.f / (e0 + e1);
        out[OUT_MASK + r * 392 + t * 2 + 0] = e0 * inv;
        out[OUT_MASK + r * 392 + t * 2 + 1] = e1 * inv;
    }

    if (r >= NROI) {   // bbox for proposal rois, same sample grid
        float4 bv = make_float4(0.f, 0.f, 0.f, 0.f);
        if (t < 196) {
            float vals[4];
#pragma unroll
            for (int a = 0; a < 4; a++) {
                const float* p = maps + (size_t)(196 + a * 49 + ij) * NPIX;
                vals[a] = samp(p, o00, o01, o10, o11, w00, w01, w10, w11);
            }
            bv = make_float4(vals[0], vals[1], vals[2], vals[3]);
        }
        red4[t] = bv;
        __syncthreads();
        for (int s = 128; s > 0; s >>= 1) {
            if (t < s) {
                red4[t].x += red4[t + s].x; red4[t].y += red4[t + s].y;
                red4[t].z += red4[t + s].z; red4[t].w += red4[t + s].w;
            }
            __syncthreads();
        }
        if (t == 0) {
            out[OUT_BBOX + r * 4 + 0] = red4[0].x / 196.f;
            out[OUT_BBOX + r * 4 + 1] = red4[0].y / 196.f;
            out[OUT_BBOX + r * 4 + 2] = red4[0].z / 196.f;
            out[OUT_BBOX + r * 4 + 3] = red4[0].w / 196.f;
        }
    }
}

// ---------------------------------------------------------------------------
// NMS stage 1: stable descending rank-sort of scores; emit order + sorted boxes
// ---------------------------------------------------------------------------
__global__ __launch_bounds__(640) void k_sort(
    const float* __restrict__ scores_ws, const float* __restrict__ ws_roisall,
    int* __restrict__ order, float* __restrict__ sbox)
{
    __shared__ float ls[NALL];
    __shared__ float lb[NALL][4];
    const int t = threadIdx.x;
    if (t < NALL) {
        ls[t] = scores_ws[t];
        lb[t][0] = ws_roisall[t * 5 + 1];
        lb[t][1] = ws_roisall[t * 5 + 2];
        lb[t][2] = ws_roisall[t * 5 + 3];
        lb[t][3] = ws_roisall[t * 5 + 4];
    }
    __syncthreads();
    if (t < NALL) {
        float s = ls[t];
        int rank = 0;
        for (int j = 0; j < NALL; j++) {
            float sj = ls[j];
            rank += (sj > s) || (sj == s && j < t);
        }
        order[rank] = t;
        float x1 = lb[t][0], y1 = lb[t][1], x2 = lb[t][2], y2 = lb[t][3];
        sbox[rank]            = x1;
        sbox[NALL + rank]     = y1;
        sbox[2 * NALL + rank] = x2;
        sbox[3 * NALL + rank] = y2;
        sbox[4 * NALL + rank] = fmaxf(x2 - x1, 0.f) * fmaxf(y2 - y1, 0.f);
    }
}

// ---------------------------------------------------------------------------
// NMS stage 2: per sorted box i, 600-bit (iou>thr) mask as 10 uint64 words
// ---------------------------------------------------------------------------
__global__ __launch_bounds__(640) void k_iou_mask(
    const float* __restrict__ sbox, unsigned long long* __restrict__ mask)
{
    const int i = blockIdx.x, t = threadIdx.x;
    const float ix1 = sbox[i], iy1 = sbox[NALL + i];
    const float ix2 = sbox[2 * NALL + i], iy2 = sbox[3 * NALL + i];
    const float ia = sbox[4 * NALL + i];
    bool pred = false;
    if (t < NALL) {
        float jx1 = sbox[t], jy1 = sbox[NALL + t];
        float jx2 = sbox[2 * NALL + t], jy2 = sbox[3 * NALL + t];
        float ja = sbox[4 * NALL + t];
        float xx1 = fmaxf(ix1, jx1), yy1 = fmaxf(iy1, jy1);
        float xx2 = fminf(ix2, jx2), yy2 = fminf(iy2, jy2);
        float inter = fmaxf(xx2 - xx1, 0.f) * fmaxf(yy2 - yy1, 0.f);
        float iou = inter / (ia + ja - inter + 1e-8f);
        pred = iou > 0.3f;
    }
    unsigned long long b = __ballot(pred ? 1 : 0);
    if ((t & 63) == 0) mask[(size_t)i * 10 + (t >> 6)] = b;
}

// ---------------------------------------------------------------------------
// NMS stage 3: greedy suppression on LDS-staged masks (round-3 version paid
// one ~200cyc L2 round-trip per serial step = ~55us; LDS + 4-deep static
// pipeline cuts it to ~8us) + emit keep[300]
// ---------------------------------------------------------------------------
__global__ __launch_bounds__(256) void k_greedy(
    const unsigned long long* __restrict__ mask, const int* __restrict__ order,
    float* __restrict__ out)
{
    __shared__ unsigned long long lm[(NALL + 4) * 10];   // +4 pad rows
    __shared__ unsigned long long kw[10];
    const int t = threadIdx.x;
    for (int i = t; i < NALL * 10; i += 256) lm[i] = mask[i];
    for (int i = NALL * 10 + t; i < (NALL + 4) * 10; i += 256) lm[i] = 0ull;
    __syncthreads();

    if (t < 64) {
        const int l = t;
        const bool act = l < 10;
        unsigned long long keepw = 0ull;
        unsigned long long c0 = act ? lm[0 * 10 + l] : 0ull;
        unsigned long long c1 = act ? lm[1 * 10 + l] : 0ull;
        unsigned long long c2 = act ? lm[2 * 10 + l] : 0ull;
        unsigned long long c3 = act ? lm[3 * 10 + l] : 0ull;
#pragma unroll 1
        for (int i = 0; i < NALL; i += 4) {
            bool s0 = __any((c0 & keepw) != 0ull);
            if (!s0 && l == (i >> 6)) keepw |= 1ull << (i & 63);
            c0 = act ? lm[(i + 4) * 10 + l] : 0ull;
            bool s1 = __any((c1 & keepw) != 0ull);
            if (!s1 && l == ((i + 1) >> 6)) keepw |= 1ull << ((i + 1) & 63);
            c1 = act ? lm[(i + 5) * 10 + l] : 0ull;
            bool s2 = __any((c2 & keepw) != 0ull);
            if (!s2 && l == ((i + 2) >> 6)) keepw |= 1ull << ((i + 2) & 63);
            c2 = act ? lm[(i + 6) * 10 + l] : 0ull;
            bool s3 = __any((c3 & keepw) != 0ull);
            if (!s3 && l == ((i + 3) >> 6)) keepw |= 1ull << ((i + 3) & 63);
            c3 = act ? lm[(i + 7) * 10 + l] : 0ull;
        }
        if (l < 10) kw[l] = keepw;
    }
    __syncthreads();
    if (t < 64) {
        int total = 0;
        for (int w = 0; w < 10; w++) total += __popcll(kw[w]);
        for (int tt = t; tt < 300; tt += 64) {
            float o = -1.f;
            if (tt < total) {
                int rem = tt, s = 0;
                for (int w = 0; w < 10; w++) {
                    int pc = __popcll(kw[w]);
                    if (rem >= pc) { rem -= pc; continue; }
                    unsigned long long word = kw[w];
                    while (rem--) word &= word - 1;
                    s = w * 64 + (__ffsll((long long)word) - 1);
                    break;
                }
                o = (float)order[s];
            }
            out[OUT_KEEP + tt] = o;
        }
    }
}

// ---------------------------------------------------------------------------
extern "C" void kernel_launch(void* const* d_in, const int* in_sizes, int n_in,
                              void* d_out, int out_size, void* d_ws, size_t ws_size,
                              hipStream_t stream)
{
    const float* feat = (const float*)d_in[0];
    const float* Wps  = (const float*)d_in[1];
    const float* bps  = (const float*)d_in[2];
    const float* Wbb  = (const float*)d_in[3];
    const float* bbb  = (const float*)d_in[4];
    const float* rois = (const float*)d_in[5];
    float* out = (float*)d_out;

    // workspace layout
    char* p = (char*)d_ws;
    float* maps_t = (float*)p;                      p += (size_t)NCOL * NPIX * 4;   // 40.14 MB
    _Float16* Wth = (_Float16*)p;                   p += (size_t)NCOLP * CIN * 2;   // 0.92 MB
    _Float16* Wtl = (_Float16*)p;                   p += (size_t)NCOLP * CIN * 2;   // 0.92 MB
    float* bias_c = (float*)p;                      p += NCOLP * 4;
    float* ws_roisall = (float*)p;                  p += NALL * 5 * 4;
    float* scores = (float*)p;                      p += NALL * 4;
    int* order = (int*)p;                           p += NALL * 4;
    float* sbox = (float*)p;                        p += NALL * 5 * 4;
    unsigned long long* mask = (unsigned long long*)p;

    hipLaunchKernelGGL(convert_W, dim3(NCOLP), dim3(256), 0, stream,
                       Wps, bps, Wbb, bbb, Wth, Wtl, bias_c);
    hipLaunchKernelGGL(gemm_mfma, dim3(1400), dim3(256), 0, stream,
                       feat, Wth, Wtl, bias_c, maps_t);
    hipLaunchKernelGGL(k_offsets_proposals, dim3(NROI), dim3(256), 0, stream,
                       maps_t, rois, ws_roisall, out);
    hipLaunchKernelGGL(k_cls_mask, dim3(NALL), dim3(256), 0, stream,
                       maps_t, ws_roisall, scores, out);
    hipLaunchKernelGGL(k_sort, dim3(1), dim3(640), 0, stream,
                       scores, ws_roisall, order, sbox);
    hipLaunchKernelGGL(k_iou_mask, dim3(NALL), dim3(640), 0, stream,
                       sbox, mask);
    hipLaunchKernelGGL(k_greedy, dim3(1), dim3(256), 0, stream,
                       mask, order, out);
}